// Round 1
// baseline (230.551 us; speedup 1.0000x reference)
//
#include <hip/hip_runtime.h>
#include <hip/hip_bf16.h>

// Problem constants (from reference setup_inputs): B,H,T,D fixed.
constexpr int B = 2, H = 16, T = 2048, D = 64;
constexpr int NS = T / 16;                   // 128 strided key positions
constexpr int WAVES = 4, BLOCK = 256;        // 4 waves per block
constexpr int CHUNKS = 16;                   // q-row chunks per (b,h)
constexpr int ROWS_PER_BLOCK = T / CHUNKS;   // 128
constexpr int ROWS_PER_WAVE = ROWS_PER_BLOCK / WAVES; // 32

// One wave handles one q-row at a time:
//  - 128 strided scores (lane l owns j=l and j=l+64), diag score via butterfly
//  - wave-wide softmax (only ~129 nonzero entries; masked -> exp underflow = 0,
//    exactly matching the fp32 reference)
//  - lane d accumulates out[d] over the 128 strided V rows + diag V row
//  - streams the full 2048-float attn row as coalesced float4 (zeros + probs),
//    so every 64B line of the 536MB attn tensor is written exactly once.
__global__ __launch_bounds__(BLOCK, 2)
void strided_attn_kernel(const float* __restrict__ q,
                         const float* __restrict__ k,
                         const float* __restrict__ v,
                         const int*   __restrict__ mask,
                         float* __restrict__ out,
                         float* __restrict__ attn)
{
    __shared__ float Ks[NS * 65];        // padded ld=65 -> (lane+d)%32 banks, conflict-free
    __shared__ float Vs[NS * 64];        // lane-consecutive reads, conflict-free
    __shared__ float q_lds[WAVES][64];
    __shared__ float p_lds[WAVES][NS];
    __shared__ int   msk[NS];

    const int blk   = blockIdx.x;
    const int bh    = blk / CHUNKS;
    const int chunk = blk % CHUNKS;
    const int b     = bh / H;

    const float* qb = q + (size_t)bh * T * D;
    const float* kb = k + (size_t)bh * T * D;
    const float* vb = v + (size_t)bh * T * D;
    const int*   mb = mask + (size_t)b * T;

    const int tid = threadIdx.x;

    // Stage strided K and V rows (rows 0,16,32,...,2032)
    for (int i = tid; i < NS * D; i += BLOCK) {
        const int j = i >> 6, d = i & 63;
        Ks[j * 65 + d] = kb[(size_t)(j * 16) * D + d];
        Vs[j * 64 + d] = vb[(size_t)(j * 16) * D + d];
    }
    if (tid < NS) msk[tid] = mb[tid * 16];
    __syncthreads();

    const int wave = tid >> 6, lane = tid & 63;
    const int row0 = chunk * ROWS_PER_BLOCK + wave * ROWS_PER_WAVE;

    for (int r = 0; r < ROWS_PER_WAVE; ++r) {
        const int qrow = row0 + r;

        // q row to LDS (lane == d)
        q_lds[wave][lane] = qb[(size_t)qrow * D + lane];
        __syncthreads();

        // Diagonal score: dot(q_row, k_row) via butterfly reduce
        float part = q_lds[wave][lane] * kb[(size_t)qrow * D + lane];
        #pragma unroll
        for (int s = 32; s > 0; s >>= 1) part += __shfl_xor(part, s, 64);
        float s_diag = part * 0.125f;
        const bool qmod = (qrow & 15) == 0;   // diag coincides with strided slot
        if (mb[qrow] == 0) s_diag = -1e9f;

        // Strided scores: lane owns j = lane and j = lane + 64
        float s0 = 0.f, s1 = 0.f;
        #pragma unroll 16
        for (int d = 0; d < D; ++d) {
            const float qv = q_lds[wave][d];          // LDS broadcast
            s0 = fmaf(qv, Ks[lane * 65 + d], s0);
            s1 = fmaf(qv, Ks[(lane + 64) * 65 + d], s1);
        }
        s0 *= 0.125f; s1 *= 0.125f;
        if (msk[lane]      == 0) s0 = -1e9f;
        if (msk[lane + 64] == 0) s1 = -1e9f;

        // Softmax over the ~129 candidate entries
        float m = fmaxf(s0, s1);
        #pragma unroll
        for (int s = 32; s > 0; s >>= 1) m = fmaxf(m, __shfl_xor(m, s, 64));
        if (!qmod) m = fmaxf(m, s_diag);

        const float e0 = __expf(s0 - m);              // masked -> exact 0 (underflow)
        const float e1 = __expf(s1 - m);
        const float ed = qmod ? 0.f : __expf(s_diag - m);
        float sum = e0 + e1;
        #pragma unroll
        for (int s = 32; s > 0; s >>= 1) sum += __shfl_xor(sum, s, 64);
        sum += ed;
        const float inv = 1.f / sum;

        p_lds[wave][lane]      = e0 * inv;
        p_lds[wave][lane + 64] = e1 * inv;
        const float p_diag = ed * inv;                // 0 when qmod or masked
        __syncthreads();

        // PV: lane == output dim d
        float acc = p_diag * vb[(size_t)qrow * D + lane];
        #pragma unroll 16
        for (int j = 0; j < NS; ++j)
            acc = fmaf(p_lds[wave][j], Vs[j * 64 + lane], acc);
        out[((size_t)bh * T + qrow) * D + lane] = acc;

        // Stream the full attn row: 512 float4s, 8 per lane, coalesced.
        float4* arow = reinterpret_cast<float4*>(attn + ((size_t)bh * T + qrow) * (size_t)T);
        const int fq = qrow >> 2;      // float4 index containing the diagonal
        const int dc = qrow & 3;       // component within it
        #pragma unroll
        for (int t = 0; t < 8; ++t) {
            const int f = t * 64 + lane;
            float4 val = make_float4(0.f, 0.f, 0.f, 0.f);
            if ((f & 3) == 0) val.x = p_lds[wave][f >> 2];   // k = 16*(f>>2)
            if (!qmod && f == fq) {                          // diagonal k == qrow
                if      (dc == 0) val.x = p_diag;
                else if (dc == 1) val.y = p_diag;
                else if (dc == 2) val.z = p_diag;
                else              val.w = p_diag;
            }
            arow[f] = val;
        }
        __syncthreads();   // protect q_lds/p_lds before next iteration
    }
}

extern "C" void kernel_launch(void* const* d_in, const int* in_sizes, int n_in,
                              void* d_out, int out_size, void* d_ws, size_t ws_size,
                              hipStream_t stream) {
    const float* q    = (const float*)d_in[0];
    const float* k    = (const float*)d_in[1];
    const float* v    = (const float*)d_in[2];
    const int*   mask = (const int*)d_in[3];

    float* out  = (float*)d_out;
    float* attn = out + (size_t)B * H * T * D;   // tuple outputs concatenated flat

    dim3 grid(B * H * CHUNKS);   // 512 blocks, 2 resident/CU (68KB LDS), 8 waves/CU
    dim3 block(BLOCK);
    hipLaunchKernelGGL(strided_attn_kernel, grid, block, 0, stream,
                       q, k, v, mask, out, attn);
}

// Round 2
// 167.635 us; speedup vs baseline: 1.3753x; 1.3753x over previous
//
#include <hip/hip_runtime.h>
#include <hip/hip_bf16.h>

// Problem constants (from reference setup_inputs): B,H,T,D fixed.
constexpr int B = 2, H = 16, T = 2048, D = 64;
constexpr int NS = T / 16;                   // 128 strided key positions
constexpr int WAVES = 4, BLOCK = 256;        // 4 waves per block
constexpr int CHUNKS = 16;                   // q-row chunks per (b,h)
constexpr int ROWS_PER_BLOCK = T / CHUNKS;   // 128
constexpr int ROWS_PER_WAVE = ROWS_PER_BLOCK / WAVES; // 32
constexpr int R = 4;                         // rows per group (amortize Ks/Vs sweeps)
constexpr int GROUPS = ROWS_PER_WAVE / R;    // 8

// One wave owns 32 q-rows, processed in groups of 4. Per group:
//  - scores: lane l owns keys j=l and j=l+64; Ks read as XOR-swizzled b128
//    (bank-group (c^(j&15))%8 spreads evenly -> conflict-free), q via LDS
//    broadcast. 4 rows share each Ks sweep.
//  - per-row diag score + wave softmax (masked -> exp underflow = exact 0).
//  - PV: lane = d; Vs b32 reads shared across the 4 rows; p via b128 broadcast.
//  - streams 4 full 8KB attn rows as coalesced float4 (each 64B line written once).
// q_lds/p_lds are per-wave private: NO __syncthreads in the row loop
// (wave64 lockstep + compiler lgkmcnt ordering suffice).
__global__ __launch_bounds__(BLOCK, 2)
void strided_attn_kernel(const float* __restrict__ q,
                         const float* __restrict__ k,
                         const float* __restrict__ v,
                         const int*   __restrict__ mask,
                         float* __restrict__ out,
                         float* __restrict__ attn)
{
    __shared__ float4 Ks4[NS][16];         // K[16j][4c..4c+3] stored at Ks4[j][c ^ (j&15)]
    __shared__ float  Vs[NS * 64];         // row-major, b32 reads conflict-free (lane=d)
    __shared__ float  q_lds[WAVES][R][64]; // per-wave private
    __shared__ float  p_lds[WAVES][R][NS]; // per-wave private
    __shared__ int    msk[NS];

    const int blk   = blockIdx.x;
    const int bh    = blk / CHUNKS;
    const int chunk = blk % CHUNKS;
    const int b     = bh / H;

    const float* qb = q + (size_t)bh * T * D;
    const float* kb = k + (size_t)bh * T * D;
    const float* vb = v + (size_t)bh * T * D;
    const int*   mb = mask + (size_t)b * T;

    const int tid = threadIdx.x;

    // Stage strided K (swizzled float4) and V (row-major float4 writes).
    // i -> (row j = i>>4, chunk c = i&15); 16 lanes cover one 256B row: coalesced.
    for (int i = tid; i < NS * 16; i += BLOCK) {
        const int j = i >> 4, c = i & 15;
        const float4 kv = *reinterpret_cast<const float4*>(kb + (size_t)(j * 16) * D + c * 4);
        const float4 vv = *reinterpret_cast<const float4*>(vb + (size_t)(j * 16) * D + c * 4);
        Ks4[j][c ^ (j & 15)] = kv;
        *reinterpret_cast<float4*>(Vs + j * 64 + c * 4) = vv;
    }
    if (tid < NS) msk[tid] = mb[tid * 16];
    __syncthreads();   // the only block-wide barrier

    const int wave = tid >> 6, lane = tid & 63;
    const int row0 = chunk * ROWS_PER_BLOCK + wave * ROWS_PER_WAVE;
    const int j0 = lane, j1 = lane + 64;
    const int xsw = lane & 15;             // same swizzle for j0 and j1 ((lane+64)&15 == lane&15)
    const int m0 = msk[j0], m1 = msk[j1];

    for (int g = 0; g < GROUPS; ++g) {
        const int grow = row0 + g * R;     // 4 consecutive q-rows

        // Stage q for 4 rows: 256 contiguous floats, one b128 per lane.
        *reinterpret_cast<float4*>(&q_lds[wave][0][0] + lane * 4) =
            *reinterpret_cast<const float4*>(qb + (size_t)grow * D + lane * 4);

        // ---- scores: 32 swizzled b128 Ks reads shared across 4 rows ----
        float s0[R] = {0.f, 0.f, 0.f, 0.f};
        float s1[R] = {0.f, 0.f, 0.f, 0.f};
        #pragma unroll
        for (int c = 0; c < 16; ++c) {
            const float4 k0 = Ks4[j0][c ^ xsw];
            const float4 k1 = Ks4[j1][c ^ xsw];
            #pragma unroll
            for (int r = 0; r < R; ++r) {
                const float4 q4 = *reinterpret_cast<const float4*>(&q_lds[wave][r][c * 4]); // broadcast
                s0[r] = fmaf(q4.w, k0.w, fmaf(q4.z, k0.z, fmaf(q4.y, k0.y, fmaf(q4.x, k0.x, s0[r]))));
                s1[r] = fmaf(q4.w, k1.w, fmaf(q4.z, k1.z, fmaf(q4.y, k1.y, fmaf(q4.x, k1.x, s1[r]))));
            }
        }

        // ---- per-row mask, diag, softmax; p -> per-wave LDS ----
        float pd[R];                       // diagonal probabilities
        bool  qmod[R];
        #pragma unroll
        for (int r = 0; r < R; ++r) {
            const int qrow = grow + r;
            float a0 = s0[r] * 0.125f, a1 = s1[r] * 0.125f;
            if (m0 == 0) a0 = -1e9f;
            if (m1 == 0) a1 = -1e9f;

            // diag score: dot(q_row, k_row) butterfly
            float part = q_lds[wave][r][lane] * kb[(size_t)qrow * D + lane];
            #pragma unroll
            for (int s = 32; s > 0; s >>= 1) part += __shfl_xor(part, s, 64);
            float sd = part * 0.125f;
            qmod[r] = (qrow & 15) == 0;    // diag coincides with a strided slot
            if (mb[qrow] == 0) sd = -1e9f;

            float m = fmaxf(a0, a1);
            #pragma unroll
            for (int s = 32; s > 0; s >>= 1) m = fmaxf(m, __shfl_xor(m, s, 64));
            if (!qmod[r]) m = fmaxf(m, sd);

            const float e0 = __expf(a0 - m);   // masked -> exact 0 (underflow)
            const float e1 = __expf(a1 - m);
            const float ed = qmod[r] ? 0.f : __expf(sd - m);
            float sum = e0 + e1;
            #pragma unroll
            for (int s = 32; s > 0; s >>= 1) sum += __shfl_xor(sum, s, 64);
            sum += ed;
            const float inv = 1.f / sum;

            p_lds[wave][r][j0] = e0 * inv;
            p_lds[wave][r][j1] = e1 * inv;
            pd[r] = ed * inv;
        }

        // ---- PV: lane = d; Vs b32 reads shared across 4 rows ----
        float acc[R];
        #pragma unroll
        for (int r = 0; r < R; ++r)
            acc[r] = pd[r] * vb[(size_t)(grow + r) * D + lane];

        #pragma unroll 8
        for (int jc = 0; jc < 32; ++jc) {
            const float v0 = Vs[(jc * 4 + 0) * 64 + lane];
            const float v1 = Vs[(jc * 4 + 1) * 64 + lane];
            const float v2 = Vs[(jc * 4 + 2) * 64 + lane];
            const float v3 = Vs[(jc * 4 + 3) * 64 + lane];
            #pragma unroll
            for (int r = 0; r < R; ++r) {
                const float4 p4 = reinterpret_cast<const float4*>(&p_lds[wave][r][0])[jc]; // broadcast
                acc[r] = fmaf(p4.w, v3, fmaf(p4.z, v2, fmaf(p4.y, v1, fmaf(p4.x, v0, acc[r]))));
            }
        }

        // ---- out + attn streaming stores (coalesced float4, each line once) ----
        #pragma unroll
        for (int r = 0; r < R; ++r) {
            const int qrow = grow + r;
            out[((size_t)bh * T + qrow) * D + lane] = acc[r];

            float4* arow = reinterpret_cast<float4*>(attn + ((size_t)bh * T + qrow) * (size_t)T);
            const int fq = qrow >> 2;      // float4 index containing the diagonal
            const int dc = qrow & 3;
            #pragma unroll
            for (int t = 0; t < 8; ++t) {
                const int f = t * 64 + lane;
                float4 val = make_float4(0.f, 0.f, 0.f, 0.f);
                if ((f & 3) == 0) val.x = p_lds[wave][r][f >> 2];   // k = 16*(f>>2)
                if (!qmod[r] && f == fq) {
                    if      (dc == 0) val.x = pd[r];
                    else if (dc == 1) val.y = pd[r];
                    else if (dc == 2) val.z = pd[r];
                    else              val.w = pd[r];
                }
                arow[f] = val;
            }
        }
    }
}

extern "C" void kernel_launch(void* const* d_in, const int* in_sizes, int n_in,
                              void* d_out, int out_size, void* d_ws, size_t ws_size,
                              hipStream_t stream) {
    const float* q    = (const float*)d_in[0];
    const float* k    = (const float*)d_in[1];
    const float* v    = (const float*)d_in[2];
    const int*   mask = (const int*)d_in[3];

    float* out  = (float*)d_out;
    float* attn = out + (size_t)B * H * T * D;   // tuple outputs concatenated flat

    dim3 grid(B * H * CHUNKS);   // 512 blocks, 2/CU (77KB LDS), 8 waves/CU
    dim3 block(BLOCK);
    hipLaunchKernelGGL(strided_attn_kernel, grid, block, 0, stream,
                       q, k, v, mask, out, attn);
}